// Round 6
// baseline (189.645 us; speedup 1.0000x reference)
//
#include <hip/hip_runtime.h>
#include <hip/hip_bf16.h>
#include <cmath>

// Problem constants: B=64, T=128, F=188, H=16
#define NROWS   8192            // B*T
#define FDIM    188
#define HDIM    16
#define NCONT   177
#define NCAT    11
#define XSTRIDE 3008            // floats per row
#define XQ      752             // float4s per row

#define CONT_THREADS (NROWS * NCONT)          // 1,449,984 = 5664 * 256
#define CONT_BLOCKS  (CONT_THREADS / 256)     // 5664
#define CAT_THREADS  (NROWS * NCAT)           // 90,112 = 352 * 256
#define CAT_BLOCKS   (CAT_THREADS / 256)      // 352

// Single fused kernel (no prep kernel, no d_ws — R5's two-kernel+ws pipeline
// tripped the graph-replay poison tripwire; this is stateless per launch).
//
// Blocks [0,5664): continuous heads, one thread per (row, cont-feature),
//   t = n*177+cf.
//   - x: each wave stages its 64 elements (4 KB) via 4 lane-DENSE dwordx4
//     loads (16 cache lines/instr instead of 64 -> kills the R1-R4 L1-miss
//     transaction bottleneck), exchanged through a wave-private LDS region
//     with rotate swizzle rot=(q+e+(e>>1))&3 (verified in R5 first launch).
//   - Wc: staged once per block into LDS, natural quad layout (verified R4).
//   - bc/eps/out: direct global, lane-dense.
// Blocks [5664,6016): categorical heads (6% of elements), R4-verified path.

__global__ __launch_bounds__(256)
void tab_fused_kernel(const float* __restrict__ x,
                      const float* __restrict__ W2a, const float* __restrict__ b2a,
                      const float* __restrict__ W3,  const float* __restrict__ b3,
                      const float* __restrict__ W4,  const float* __restrict__ b4,
                      const float* __restrict__ W6,  const float* __restrict__ b6,
                      const float* __restrict__ W7,  const float* __restrict__ b7,
                      const float* __restrict__ Wc,  const float* __restrict__ bc,
                      const float* __restrict__ eps,
                      float* __restrict__ out)
{
    __shared__ float4 sW[8 * NCONT];   // 22656 B: sW[k*177+cf] = Wc quad k of cf
    __shared__ float4 xex[4][256];     // 16384 B: 4 KB per wave, wave-private
                                       // total 39040 B -> 4 blocks/CU

    const int tid  = threadIdx.x;
    const int wave = tid >> 6;
    const int lane = tid & 63;

    if (blockIdx.x < CONT_BLOCKS) {
        // ---- stage Wc (coalesced float4 reads; i == cf*8+k exactly) ----
        const float4* wp4 = reinterpret_cast<const float4*>(Wc);
        for (int i = tid; i < NCONT * 8; i += 256) {
            int cf = i >> 3, k = i & 7;
            sW[k * NCONT + cf] = wp4[i];
        }

        // ---- stage x: 4 dense dwordx4 loads, swizzled scatter into LDS ----
        const int t0 = blockIdx.x * 256 + (wave << 6);   // wave's first element
        const float4* x4 = reinterpret_cast<const float4*>(x);
        #pragma unroll
        for (int k = 0; k < 4; ++k) {
            const int idx = lane + 64 * k;      // 0..255 over 4 iters
            const int e   = idx >> 2;           // local element 0..63
            const int q   = idx & 3;            // x-quad of that element
            const int te  = t0 + e;
            const int n   = te / NCONT;
            const int cf  = te - n * NCONT;
            float4 v = x4[n * XQ + 44 + cf * 4 + q];    // (11+cf)*4 == 44+4cf
            xex[wave][(e << 2) + ((q + e + (e >> 1)) & 3)] = v;
        }

        // this thread's element
        const int t  = t0 + lane;
        const int n  = t / NCONT;
        const int cf = t - n * NCONT;

        const float2 bb = reinterpret_cast<const float2*>(bc)[cf];  // L1-resident
        const float  ev = eps[t];               // eps is [N,177] flat == t

        __syncthreads();   // covers block-wide sW staging + wave xex writes

        float4 a0 = xex[wave][(lane << 2) + ((0 + lane + (lane >> 1)) & 3)];
        float4 a1 = xex[wave][(lane << 2) + ((1 + lane + (lane >> 1)) & 3)];
        float4 a2 = xex[wave][(lane << 2) + ((2 + lane + (lane >> 1)) & 3)];
        float4 a3 = xex[wave][(lane << 2) + ((3 + lane + (lane >> 1)) & 3)];

        float4 w0 = sW[0 * NCONT + cf], w1 = sW[1 * NCONT + cf];
        float4 w2 = sW[2 * NCONT + cf], w3 = sW[3 * NCONT + cf];
        float4 w4 = sW[4 * NCONT + cf], w5 = sW[5 * NCONT + cf];
        float4 w6 = sW[6 * NCONT + cf], w7 = sW[7 * NCONT + cf];

        // quad k holds (m,s) weights for x-elements 2k, 2k+1 (verified R4)
        float m = bb.x, s = bb.y;
        m = fmaf(a0.x, w0.x, m); s = fmaf(a0.x, w0.y, s);
        m = fmaf(a0.y, w0.z, m); s = fmaf(a0.y, w0.w, s);
        m = fmaf(a0.z, w1.x, m); s = fmaf(a0.z, w1.y, s);
        m = fmaf(a0.w, w1.z, m); s = fmaf(a0.w, w1.w, s);
        m = fmaf(a1.x, w2.x, m); s = fmaf(a1.x, w2.y, s);
        m = fmaf(a1.y, w2.z, m); s = fmaf(a1.y, w2.w, s);
        m = fmaf(a1.z, w3.x, m); s = fmaf(a1.z, w3.y, s);
        m = fmaf(a1.w, w3.z, m); s = fmaf(a1.w, w3.w, s);
        m = fmaf(a2.x, w4.x, m); s = fmaf(a2.x, w4.y, s);
        m = fmaf(a2.y, w4.z, m); s = fmaf(a2.y, w4.w, s);
        m = fmaf(a2.z, w5.x, m); s = fmaf(a2.z, w5.y, s);
        m = fmaf(a2.w, w5.z, m); s = fmaf(a2.w, w5.w, s);
        m = fmaf(a3.x, w6.x, m); s = fmaf(a3.x, w6.y, s);
        m = fmaf(a3.y, w6.z, m); s = fmaf(a3.y, w6.w, s);
        m = fmaf(a3.z, w7.x, m); s = fmaf(a3.z, w7.y, s);
        m = fmaf(a3.w, w7.z, m); s = fmaf(a3.w, w7.w, s);

        // fast tanh: 1 - 2/(e^{2x}+1); clamp keeps __expf in range
        float mc   = fminf(fmaxf(m, -10.0f), 10.0f);
        float mean = 1.0f - 2.0f / (__expf(2.0f * mc) + 1.0f);
        float stdv = 1.0f / (1.0f + __expf(-s));

        out[(size_t)n * FDIM + NCAT + cf] = fmaf(stdv, ev, mean);
    } else {
        // ---------------- categorical heads (R4-verified) ----------------
        const int t = (blockIdx.x - CONT_BLOCKS) * 256 + tid;   // < CAT_THREADS
        const int n = t / NCAT;
        const int f = t - n * NCAT;

        const float4* xq = reinterpret_cast<const float4*>(
            x + (size_t)n * XSTRIDE + (size_t)f * HDIM);
        float4 a0 = xq[0], a1 = xq[1], a2 = xq[2], a3 = xq[3];
        float xv[16] = { a0.x, a0.y, a0.z, a0.w,
                         a1.x, a1.y, a1.z, a1.w,
                         a2.x, a2.y, a2.z, a2.w,
                         a3.x, a3.y, a3.z, a3.w };

        const float *W, *bb;
        int odim;
        if (f < 4)      { W = W2a + f * HDIM * 2;      bb = b2a + f * 2;      odim = 2; }
        else if (f < 6) { W = W3 + (f - 4) * HDIM * 3; bb = b3 + (f - 4) * 3; odim = 3; }
        else if (f < 7) { W = W4;                      bb = b4;               odim = 4; }
        else if (f < 8) { W = W6;                      bb = b6;               odim = 6; }
        else            { W = W7 + (f - 8) * HDIM * 7; bb = b7 + (f - 8) * 7; odim = 7; }

        float best = -1e30f;
        int   bi   = 0;
        for (int o = 0; o < odim; ++o) {
            float acc = bb[o];                        // 4.3 KB total -> L1-resident
            #pragma unroll
            for (int d = 0; d < 16; ++d) acc = fmaf(xv[d], W[d * odim + o], acc);
            if (acc > best) { best = acc; bi = o; }   // strict > == first-max (jnp.argmax)
        }
        out[(size_t)n * FDIM + f] = (float)bi;
    }
}

extern "C" void kernel_launch(void* const* d_in, const int* in_sizes, int n_in,
                              void* d_out, int out_size, void* d_ws, size_t ws_size,
                              hipStream_t stream) {
    const float* x   = (const float*)d_in[0];
    const float* W2a = (const float*)d_in[1];
    const float* b2a = (const float*)d_in[2];
    const float* W3  = (const float*)d_in[3];
    const float* b3  = (const float*)d_in[4];
    const float* W4  = (const float*)d_in[5];
    const float* b4  = (const float*)d_in[6];
    const float* W6  = (const float*)d_in[7];
    const float* b6  = (const float*)d_in[8];
    const float* W7  = (const float*)d_in[9];
    const float* b7  = (const float*)d_in[10];
    const float* Wc  = (const float*)d_in[11];
    const float* bc  = (const float*)d_in[12];
    const float* eps = (const float*)d_in[13];
    float* out = (float*)d_out;

    hipLaunchKernelGGL(tab_fused_kernel, dim3(CONT_BLOCKS + CAT_BLOCKS), dim3(256), 0, stream,
                       x, W2a, b2a, W3, b3, W4, b4, W6, b6, W7, b7, Wc, bc, eps, out);
}